// Round 16
// baseline (242.308 us; speedup 1.0000x reference)
//
#include <hip/hip_runtime.h>
#include <stdint.h>

// Shapes: B=16 T=8 C=2048 H=16 W=8 -> C8=256 C4=512 HW=128 NP=4
// NIMG = B*T = 128, M = NIMG*HW = 16384, Ncat = 2*C8 = 512, K = 2048

typedef _Float16 f16;
typedef _Float16 f16x2 __attribute__((ext_vector_type(2)));
typedef _Float16 f16x4 __attribute__((ext_vector_type(4)));
typedef _Float16 f16x8 __attribute__((ext_vector_type(8)));
typedef float f32x4 __attribute__((ext_vector_type(4)));

typedef const void __attribute__((address_space(1)))* gptr1;
typedef void __attribute__((address_space(3)))* lptr3;

__device__ __forceinline__ void gload16(const void* g, void* l) {
  __builtin_amdgcn_global_load_lds((gptr1)g, (lptr3)l, 16, 0, 0);
}

__device__ __forceinline__ float sigmoidf_(float x) { return 1.f / (1.f + expf(-x)); }

#define WAIT_VM4 asm volatile("s_waitcnt vmcnt(4)" ::: "memory")
#define WAIT_VM0 asm volatile("s_waitcnt vmcnt(0)" ::: "memory")
#define WAIT_LGKM6 asm volatile("s_waitcnt lgkmcnt(6)" ::: "memory")
#define WAIT_LGKM1 asm volatile("s_waitcnt lgkmcnt(1)" ::: "memory")
#define WAIT_LGKM0 asm volatile("s_waitcnt lgkmcnt(0)" ::: "memory")
#define SBAR __builtin_amdgcn_s_barrier()
#define SCHED0 __builtin_amdgcn_sched_barrier(0)

// ---------------- Prep: Wf f16 pre-swizzled + LDS-tiled weight transposes ----------------
__global__ __launch_bounds__(256) void kPP(const float* __restrict__ gw, const float* __restrict__ gs,
                                           const float* __restrict__ bw, const float* __restrict__ bs,
                                           const float* __restrict__ gg_w, const float* __restrict__ gg_s,
                                           const float* __restrict__ tte_w, const float* __restrict__ tte_s,
                                           const float* __restrict__ thw, const float* __restrict__ w1,
                                           const float* __restrict__ w2,
                                           f16* __restrict__ Wf,
                                           float* __restrict__ ggT, float* __restrict__ tteT,
                                           float* __restrict__ thwT, float* __restrict__ w1T,
                                           float* __restrict__ w2T) {
  __shared__ __align__(16) float TL[64][65];
  int t = threadIdx.x;
  int bid = blockIdx.x;
  if (bid < 512) {                   // Wf: 512 o * 256 chunks
    int id = bid * 256 + t;
    int o = id >> 8, cch = id & 255;
    float s; const float* row;
    if (o < 256) { s = gs[o]; row = gw + (size_t)o * 2048; }
    else         { s = bs[o - 256]; row = bw + (size_t)(o - 256) * 2048; }
    int kb = cch >> 3, sub = cch & 7;
    int subd = sub ^ (o & 7);
    f16x8 h8;
    for (int j = 0; j < 8; ++j)
      h8[j] = (f16)(row[cch * 8 + j] * s);
    size_t ob = (size_t)o * 2048 + (size_t)kb * 64 + (size_t)subd * 8;
    *(f16x8*)(Wf + ob) = h8;
    return;
  }
  int tb = bid - 512;
  const float* src; float* dst; const float* scale = nullptr; int R, C;
  if (tb < 128)      { src = thw;   dst = thwT; R = 256;  C = 2048; }
  else if (tb < 256) { tb -= 128; src = w2;  dst = w2T;  R = 2048; C = 256; }
  else if (tb < 288) { tb -= 256; src = w1;  dst = w1T;  R = 256;  C = 512; }
  else if (tb < 296) { tb -= 288; src = gg_w;  dst = ggT;  scale = gg_s;  R = 128; C = 256; }
  else               { tb -= 296; src = tte_w; dst = tteT; scale = tte_s; R = 128; C = 256; }
  int tpc = C >> 6;
  int r0 = (tb / tpc) * 64, c0 = (tb % tpc) * 64;
  int i16 = t >> 4, j4 = (t & 15) * 4;
  for (int s = 0; s < 4; ++s) {
    int i = i16 + s * 16;
    float4 v = *(const float4*)(src + (size_t)(r0 + i) * C + c0 + j4);
    TL[i][j4 + 0] = v.x; TL[i][j4 + 1] = v.y; TL[i][j4 + 2] = v.z; TL[i][j4 + 3] = v.w;
  }
  __syncthreads();
  for (int s = 0; s < 4; ++s) {
    int j = i16 + s * 16;
    float4 w;
    w.x = TL[j4 + 0][j]; w.y = TL[j4 + 1][j]; w.z = TL[j4 + 2][j]; w.w = TL[j4 + 3][j];
    if (scale) {
      w.x *= scale[r0 + j4 + 0]; w.y *= scale[r0 + j4 + 1];
      w.z *= scale[r0 + j4 + 2]; w.w *= scale[r0 + j4 + 3];
    }
    *(float4*)(dst + (size_t)(c0 + j) * R + r0 + j4) = w;
  }
}

// ---------------- Stage A GEMM, 2 blocks/CU variant ----------------
// BM=64 BN=256 BK=64; 512 threads = 8 waves (2M x 4N), 32x64/wave; grid 512 = 2/CU.
// 2 LDS buffers x 40KB = 80KB. A fp32->f16 reg-staged from re_featmap; W via gload_lds.
// Per step s: barrier -> issue A(s+1)[8 dwords->regs] + W(s+1)[4 gloads->nxt] ->
//   12 frag reads(cur) -> lgkm(6) -> 8 MFMA -> vmcnt(4) -> 1 ds_write_b128 A(s+1)->nxt
//   -> lgkm(1) -> 8 MFMA -> lgkm(0)+vmcnt(0).
__global__ __launch_bounds__(512, 4) void kGemm8(const float* __restrict__ X, const f16* __restrict__ Wf,
                                                 const float* __restrict__ gamma_b, const float* __restrict__ beta_b,
                                                 f16* __restrict__ gammaFh, f16* __restrict__ betaFh) {
  __shared__ __align__(16) f16 S[2][20480];   // per buffer: A[0:4096], B[4096:20480] (f16 idx)
  int t = threadIdx.x;
  int lane = t & 63, wid = t >> 6;
  int wr = wid >> 2, wc = wid & 3;
  int bid = blockIdx.x;
  int bx = (bid & 7) * 32 + (bid >> 4);      // XCD pairing: by=0/1 share A on one XCD
  int by = (bid >> 3) & 1;
  int n = bx >> 1, hh = bx & 1;
  size_t N0 = (size_t)by * 256;
  int row8 = wid * 8 + (lane >> 3);
  int sl = lane & 7;
  int fr = lane & 15, fq = lane >> 4;
  f32x4 acc[2][4] = {};
  f16x8 a[4], b[8];
  float ar[8];

  const float* Xb = X + (size_t)n * 262144 + hh * 64;
  int hwl = lane;                            // 0..63 (within this block's hw half)
  int kg8 = wid * 8;                         // 8 k per thread
  int woA = hwl * 64 + ((wid ^ (hwl & 7)) << 3);

  const char* WB = (const char*)Wf;
  const size_t woff0 = (N0 + row8) * 4096 + (size_t)sl * 16;
  const size_t woff1 = (N0 + 64 + row8) * 4096 + (size_t)sl * 16;
  const size_t woff2 = (N0 + 128 + row8) * 4096 + (size_t)sl * 16;
  const size_t woff3 = (N0 + 192 + row8) * 4096 + (size_t)sl * 16;

#define AISSUE(s) do {                                                             \
    const float* p_ = Xb + ((s) * 64 + kg8) * 128 + hwl;                           \
    _Pragma("unroll") for (int j_ = 0; j_ < 8; ++j_)                               \
      ar[j_] = p_[j_ * 128];                                                       \
  } while (0)

#define WSTAGE(dst, s) do {                                                        \
    int koff_ = (s) << 7;                                                          \
    char* l_ = (char*)(dst) + 8192 + wid * 1024;                                   \
    gload16(WB + woff0 + koff_, l_);                                               \
    gload16(WB + woff1 + koff_, l_ + 8192);                                        \
    gload16(WB + woff2 + koff_, l_ + 16384);                                       \
    gload16(WB + woff3 + koff_, l_ + 24576);                                       \
  } while (0)

#define AWRITE(dst) do {                                                           \
    f16x8 h_;                                                                      \
    _Pragma("unroll") for (int i_ = 0; i_ < 8; ++i_)                               \
      h_[i_] = (f16)ar[i_];                                                        \
    *(f16x8*)((f16*)(dst) + woA) = h_;                                             \
  } while (0)

#define LOADG(buf, g) do {                                                         \
    const f16* bA_ = (const f16*)(buf);                                            \
    const f16* bB_ = bA_ + 4096;                                                   \
    int cg_ = (g) * 4 + fq;                                                        \
    _Pragma("unroll") for (int mi = 0; mi < 2; ++mi) {                             \
      int m_ = wr * 32 + mi * 16 + fr;                                             \
      a[(g) * 2 + mi] = *(const f16x8*)(bA_ + m_ * 64 + ((cg_ ^ (m_ & 7)) << 3));  \
    }                                                                              \
    _Pragma("unroll") for (int ni = 0; ni < 4; ++ni) {                             \
      int n_ = wc * 64 + ni * 16 + fr;                                             \
      b[(g) * 4 + ni] = *(const f16x8*)(bB_ + n_ * 64 + ((cg_ ^ (n_ & 7)) << 3));  \
    }                                                                              \
  } while (0)

#define MFMA_G(g) do {                                                             \
    _Pragma("unroll") for (int mi = 0; mi < 2; ++mi)                               \
      _Pragma("unroll") for (int ni = 0; ni < 4; ++ni)                             \
        acc[mi][ni] = __builtin_amdgcn_mfma_f32_16x16x32_f16(                      \
            a[(g) * 2 + mi], b[(g) * 4 + ni], acc[mi][ni], 0, 0, 0);               \
  } while (0)

#define STEP(cur, nxt, s) do {                                                     \
    SBAR;                                                                          \
    if ((s) <= 30) { AISSUE((s) + 1); WSTAGE(nxt, (s) + 1); }                      \
    SCHED0;                                                                        \
    LOADG(cur, 0);                                                                 \
    SCHED0;                                                                        \
    LOADG(cur, 1);                                                                 \
    WAIT_LGKM6;                                                                    \
    SCHED0;                                                                        \
    __builtin_amdgcn_s_setprio(1);                                                 \
    MFMA_G(0);                                                                     \
    if ((s) <= 30) {                                                               \
      WAIT_VM4;                                                                    \
      SCHED0;                                                                      \
      AWRITE(nxt);                                                                 \
      WAIT_LGKM1;                                                                  \
      SCHED0;                                                                      \
      MFMA_G(1);                                                                   \
      __builtin_amdgcn_s_setprio(0);                                               \
      WAIT_LGKM0;                                                                  \
      WAIT_VM0;                                                                    \
    } else {                                                                       \
      WAIT_LGKM0;                                                                  \
      SCHED0;                                                                      \
      MFMA_G(1);                                                                   \
      __builtin_amdgcn_s_setprio(0);                                               \
    }                                                                              \
  } while (0)

  // prologue: A(0)->regs->buf0, W(0)->buf0
  AISSUE(0); WSTAGE(&S[0][0], 0);
  SCHED0;
  WAIT_VM4;
  SCHED0;
  AWRITE(&S[0][0]);
  WAIT_VM0;
  WAIT_LGKM0;

  for (int base = 0; base < 32; base += 2) {
    STEP(&S[0][0], &S[1][0], base);
    STEP(&S[1][0], &S[0][0], base + 1);
  }
#undef STEP
#undef MFMA_G
#undef LOADG
#undef AWRITE
#undef WSTAGE
#undef AISSUE

  // epilogue: +bias, relu, store f16 to gammaFh/betaFh[n][o][hw]
  const float* bias = by ? beta_b : gamma_b;
  f16* outb = by ? betaFh : gammaFh;
#pragma unroll
  for (int mi = 0; mi < 2; ++mi) {
    int hwb = wr * 32 + mi * 16 + fq * 4;     // C/D: row = (lane>>4)*4 + reg
#pragma unroll
    for (int ni = 0; ni < 4; ++ni) {
      int o = wc * 64 + ni * 16 + fr;         // C/D: col = lane&15
      float bb = bias[o];
      f32x4 v = acc[mi][ni];
      f16x4 w;
      w[0] = (f16)fmaxf(v[0] + bb, 0.f);
      w[1] = (f16)fmaxf(v[1] + bb, 0.f);
      w[2] = (f16)fmaxf(v[2] + bb, 0.f);
      w[3] = (f16)fmaxf(v[3] + bb, 0.f);
      *(f16x4*)(outb + (size_t)n * 32768 + (size_t)o * 128 + hh * 64 + hwb) = w;
    }
  }
}

// ---------------- Merged Theta2 + Ta ----------------
__global__ __launch_bounds__(256) void kTT(const float* __restrict__ vect, const float* __restrict__ thwT,
                                           float* __restrict__ P,
                                           const float* __restrict__ embed, const float* __restrict__ tteT,
                                           const float* __restrict__ tte_b, const float* __restrict__ te_w,
                                           float* __restrict__ Sta) {
  __shared__ float V[512];
  __shared__ __align__(16) float E[256 * 64];
  __shared__ float Red[16 * 64];
  int bid = blockIdx.x;
  int t = threadIdx.x;
  if (bid < 512) {
    int bt = bid & 127, kq = bid >> 7;
    const float* src = vect + (size_t)bt * 2048 + kq * 512;
    if (t < 128) *(float4*)(V + t * 4) = *(const float4*)(src + t * 4);
    __syncthreads();
    const float* wp = thwT + (size_t)kq * 512 * 256 + t;
    float acc = 0.f;
#pragma unroll 8
    for (int c = 0; c < 512; ++c)
      acc = fmaf(wp[(size_t)c * 256], V[c], acc);
    P[((size_t)kq * 128 + bt) * 256 + t] = acc;
    return;
  }
  int i = bid - 512;
  int n = i & 63, gate = (i >> 6) & 1, hh = (i >> 7) & 1;
  int b = n >> 2, p = n & 3;
  const float* eA = embed + (size_t)(b * 8 + 2 * p + gate) * 16384 + hh * 64;
  const float* eB = embed + (size_t)(b * 8 + 2 * p + 1 - gate) * 16384 + hh * 64;
  for (int r = 0; r < 8; ++r) {
    int f = r * 256 + t;
    int ch = f >> 4, q = (f & 15) * 4;
    *(float4*)(E + ch * 64 + q) = *(const float4*)(eA + (size_t)ch * 128 + q);
  }
  for (int r = 0; r < 8; ++r) {
    int f = r * 256 + t;
    int ch = f >> 4, q = (f & 15) * 4;
    *(float4*)(E + (128 + ch) * 64 + q) = *(const float4*)(eB + (size_t)ch * 128 + q);
  }
  __syncthreads();
  int ty = t >> 4, tx = t & 15;
  float acc[8][4] = {};
  for (int c = 0; c < 256; ++c) {
    float w8[8];
    *(float4*)w8 = *(const float4*)(tteT + (size_t)c * 128 + ty * 8);
    *(float4*)(w8 + 4) = *(const float4*)(tteT + (size_t)c * 128 + ty * 8 + 4);
    float4 g = *(const float4*)(E + c * 64 + tx * 4);
    for (int ii = 0; ii < 8; ++ii) {
      acc[ii][0] = fmaf(w8[ii], g.x, acc[ii][0]);
      acc[ii][1] = fmaf(w8[ii], g.y, acc[ii][1]);
      acc[ii][2] = fmaf(w8[ii], g.z, acc[ii][2]);
      acc[ii][3] = fmaf(w8[ii], g.w, acc[ii][3]);
    }
  }
  float par[4] = {0.f, 0.f, 0.f, 0.f};
  for (int ii = 0; ii < 8; ++ii) {
    int o = ty * 8 + ii;
    float tb = tte_b[o], tw = te_w[o];
    for (int j = 0; j < 4; ++j)
      par[j] += tw * fmaxf(acc[ii][j] + tb, 0.f);
  }
  for (int j = 0; j < 4; ++j) Red[ty * 64 + tx * 4 + j] = par[j];
  __syncthreads();
  if (t < 64) {
    float s = 0.f;
    for (int g = 0; g < 16; ++g) s += Red[g * 64 + t];
    Sta[(size_t)gate * 8192 + n * 128 + hh * 64 + t] = s;
  }
}

// ---------------- Merged MlpA + Gs (gammaF/betaF are f16) ----------------
__global__ __launch_bounds__(256) void kAG(const float* __restrict__ P, const float* __restrict__ thb,
                                           const float* __restrict__ w1T, const float* __restrict__ b1,
                                           float* __restrict__ h1,
                                           const f16* __restrict__ gammaFh, const f16* __restrict__ betaFh,
                                           float* __restrict__ Gs0, float* __restrict__ Gs1) {
  __shared__ float x0[256], x1[256];
  __shared__ float ra[256], rb[256];
  __shared__ __align__(16) float As[16 * 128];
  __shared__ __align__(16) float Bs[16 * 64];
  int bid = blockIdx.x;
  int t = threadIdx.x;
  if (bid < 256) {
    int bp = bid & 63, och = bid >> 6;
    int b = bp >> 2, p = bp & 3;
    int bt0 = b * 8 + 2 * p, bt1 = bt0 + 1;
    {
      float a0 = 0.f, a1 = 0.f;
      for (int q = 0; q < 4; ++q) {
        a0 += P[((size_t)q * 128 + bt0) * 256 + t];
        a1 += P[((size_t)q * 128 + bt1) * 256 + t];
      }
      float tb = thb[t];
      x0[t] = fmaxf(a0 + tb, 0.f);
      x1[t] = fmaxf(a1 + tb, 0.f);
    }
    __syncthreads();
    int o = och * 64 + (t & 63);
    int ks = t >> 6;
    const float* xa = (ks < 2) ? x0 : x1;
    const float* xb = (ks < 2) ? x1 : x0;
    int kbase = ks * 128;
    int xoff = (ks < 2) ? kbase : kbase - 256;
    float aa = 0.f, ab = 0.f;
#pragma unroll 8
    for (int ii = 0; ii < 128; ++ii) {
      float w = w1T[(size_t)(kbase + ii) * 256 + o];
      aa = fmaf(w, xa[xoff + ii], aa);
      ab = fmaf(w, xb[xoff + ii], ab);
    }
    ra[t] = aa;
    rb[t] = ab;
    __syncthreads();
    if (t < 64) {
      float sa = ra[t] + ra[64 + t] + ra[128 + t] + ra[192 + t];
      float sb = rb[t] + rb[64 + t] + rb[128 + t] + rb[192 + t];
      float bb = b1[o];
      h1[((size_t)bp * 2) * 256 + o] = fmaxf(sa + bb, 0.f);
      h1[((size_t)bp * 2 + 1) * 256 + o] = fmaxf(sb + bb, 0.f);
    }
    return;
  }
  int i = bid - 256;
  int n = i & 63, which = (i >> 6) & 1, th = (i >> 7) & 1;
  int b = n >> 2, p = n & 3;
  int tg = 2 * p + which;
  int tb = 2 * p + 1 - which;
  const f16* A = gammaFh + (size_t)(b * 8 + tg) * 32768;
  const f16* Bm = betaFh + (size_t)(b * 8 + tb) * 32768;
  float* out = (which ? Gs1 : Gs0) + (size_t)n * 16384;
  int ty = t >> 4, tx = t & 15;
  float acc[8][4] = {};
  for (int c0 = 0; c0 < 256; c0 += 16) {
    {
      int cc = t >> 4, col8 = (t & 15) * 8;
      f16x8 v = *(const f16x8*)(A + (size_t)(c0 + cc) * 128 + col8);
      for (int j = 0; j < 8; ++j) As[cc * 128 + col8 + j] = (float)v[j];
    }
    if (t < 128) {
      int cc = t >> 3, col8 = (t & 7) * 8;
      f16x8 v = *(const f16x8*)(Bm + (size_t)(c0 + cc) * 128 + th * 64 + col8);
      for (int j = 0; j < 8; ++j) Bs[cc * 64 + col8 + j] = (float)v[j];
    }
    __syncthreads();
    for (int cc = 0; cc < 16; ++cc) {
      float a8[8];
      *(float4*)a8 = *(const float4*)(As + cc * 128 + ty * 8);
      *(float4*)(a8 + 4) = *(const float4*)(As + cc * 128 + ty * 8 + 4);
      float4 b4 = *(const float4*)(Bs + cc * 64 + tx * 4);
      for (int ii = 0; ii < 8; ++ii) {
        acc[ii][0] = fmaf(a8[ii], b4.x, acc[ii][0]);
        acc[ii][1] = fmaf(a8[ii], b4.y, acc[ii][1]);
        acc[ii][2] = fmaf(a8[ii], b4.z, acc[ii][2]);
        acc[ii][3] = fmaf(a8[ii], b4.w, acc[ii][3]);
      }
    }
    __syncthreads();
  }
  for (int ii = 0; ii < 8; ++ii) {
    *(float4*)(out + (size_t)(ty * 8 + ii) * 128 + th * 64 + tx * 4) =
        make_float4(acc[ii][0], acc[ii][1], acc[ii][2], acc[ii][3]);
  }
}

// ---------------- Merged MlpB + Gj ----------------
__global__ __launch_bounds__(256) void kBG(const float* __restrict__ h1, const float* __restrict__ w2T,
                                           const float* __restrict__ b2,
                                           float* __restrict__ p00, float* __restrict__ p01,
                                           const float* __restrict__ Gs0, const float* __restrict__ Gs1,
                                           const float* __restrict__ ggT, const float* __restrict__ gg_b,
                                           const float* __restrict__ te_w, float* __restrict__ Sgj) {
  __shared__ float ha[256], hb[256];
  __shared__ float G0h[64 * 129];
  __shared__ __align__(16) float G1c[128 * 64];
  __shared__ float Red[16 * 64];
  int bid = blockIdx.x;
  int t = threadIdx.x;
  if (bid < 512) {
    int bp = bid & 63, chc = bid >> 6;
    ha[t] = h1[((size_t)bp * 2) * 256 + t];
    hb[t] = h1[((size_t)bp * 2 + 1) * 256 + t];
    __syncthreads();
    int ch = chc * 256 + t;
    float sa = 0.f, sb = 0.f;
#pragma unroll 8
    for (int k = 0; k < 256; ++k) {
      float w = w2T[(size_t)k * 2048 + ch];
      sa = fmaf(w, ha[k], sa);
      sb = fmaf(w, hb[k], sb);
    }
    p00[(size_t)bp * 2048 + ch] = sigmoidf_(sa + b2[ch]);
    p01[(size_t)bp * 2048 + ch] = sigmoidf_(sb + b2[ch]);
    return;
  }
  int i = bid - 512;
  int n = i & 63, gate = (i >> 6) & 1, hh = (i >> 7) & 1;
  const float* srcT = (gate == 0 ? Gs0 : Gs1) + (size_t)n * 16384;
  const float* srcC = (gate == 0 ? Gs1 : Gs0) + (size_t)n * 16384;
  for (int r = 0; r < 8; ++r) {
    int f = r * 256 + t;
    int hwl = f >> 5, c4 = (f & 31) * 4;
    float4 v = *(const float4*)(srcT + (size_t)(hh * 64 + hwl) * 128 + c4);
    G0h[hwl * 129 + c4 + 0] = v.x;
    G0h[hwl * 129 + c4 + 1] = v.y;
    G0h[hwl * 129 + c4 + 2] = v.z;
    G0h[hwl * 129 + c4 + 3] = v.w;
  }
  for (int r = 0; r < 8; ++r) {
    int f = r * 256 + t;
    int c = f >> 4, q = (f & 15) * 4;
    *(float4*)(G1c + c * 64 + q) = *(const float4*)(srcC + (size_t)c * 128 + hh * 64 + q);
  }
  __syncthreads();
  int ty = t >> 4, tx = t & 15;
  float acc[8][4] = {};
  for (int c = 0; c < 128; ++c) {
    float w8[8];
    *(float4*)w8 = *(const float4*)(ggT + (size_t)c * 128 + ty * 8);
    *(float4*)(w8 + 4) = *(const float4*)(ggT + (size_t)c * 128 + ty * 8 + 4);
    float g4[4];
    for (int j = 0; j < 4; ++j) g4[j] = G0h[(tx * 4 + j) * 129 + c];
    for (int ii = 0; ii < 8; ++ii)
      for (int j = 0; j < 4; ++j)
        acc[ii][j] = fmaf(w8[ii], g4[j], acc[ii][j]);
  }
  for (int c = 0; c < 128; ++c) {
    float w8[8];
    *(float4*)w8 = *(const float4*)(ggT + (size_t)(128 + c) * 128 + ty * 8);
    *(float4*)(w8 + 4) = *(const float4*)(ggT + (size_t)(128 + c) * 128 + ty * 8 + 4);
    float4 g = *(const float4*)(G1c + c * 64 + tx * 4);
    for (int ii = 0; ii < 8; ++ii) {
      acc[ii][0] = fmaf(w8[ii], g.x, acc[ii][0]);
      acc[ii][1] = fmaf(w8[ii], g.y, acc[ii][1]);
      acc[ii][2] = fmaf(w8[ii], g.z, acc[ii][2]);
      acc[ii][3] = fmaf(w8[ii], g.w, acc[ii][3]);
    }
  }
  float par[4] = {0.f, 0.f, 0.f, 0.f};
  for (int ii = 0; ii < 8; ++ii) {
    int o = ty * 8 + ii;
    float gb = gg_b[o], tw = te_w[128 + o];
    for (int j = 0; j < 4; ++j)
      par[j] += tw * fmaxf(acc[ii][j] + gb, 0.f);
  }
  for (int j = 0; j < 4; ++j) Red[ty * 64 + tx * 4 + j] = par[j];
  __syncthreads();
  if (t < 64) {
    float s = 0.f;
    for (int g = 0; g < 16; ++g) s += Red[g * 64 + t];
    Sgj[(size_t)gate * 8192 + n * 128 + hh * 64 + t] = s;
  }
}

// ---------------- final elementwise (gate sigmoid fused): out = relu(p00*pa*f0 + p01*pb*f1)^2 ----
__global__ __launch_bounds__(256) void kFinal(const float* __restrict__ featmap, const float* __restrict__ p00,
                                              const float* __restrict__ p01, const float* __restrict__ Sta,
                                              const float* __restrict__ Sgj, const float* __restrict__ te_s,
                                              const float* __restrict__ te_b, float* __restrict__ out) {
  int fid = blockIdx.x * 256 + threadIdx.x;
  int h4 = (fid & 31) * 4;
  int c = (fid >> 5) & 2047;
  int bp = fid >> 16;
  int b = bp >> 2, p = bp & 3;
  float ga = p00[(size_t)bp * 2048 + c];
  float gb = p01[(size_t)bp * 2048 + c];
  float ts = te_s[0], tbv = te_b[0];
  float4 sa0 = *(const float4*)(Sta + (size_t)bp * 128 + h4);
  float4 sg0 = *(const float4*)(Sgj + (size_t)bp * 128 + h4);
  float4 sa1 = *(const float4*)(Sta + 8192 + (size_t)bp * 128 + h4);
  float4 sg1 = *(const float4*)(Sgj + 8192 + (size_t)bp * 128 + h4);
  float4 pa4, pb4;
  pa4.x = sigmoidf_(ts * (sa0.x + sg0.x) + tbv);
  pa4.y = sigmoidf_(ts * (sa0.y + sg0.y) + tbv);
  pa4.z = sigmoidf_(ts * (sa0.z + sg0.z) + tbv);
  pa4.w = sigmoidf_(ts * (sa0.w + sg0.w) + tbv);
  pb4.x = sigmoidf_(ts * (sa1.x + sg1.x) + tbv);
  pb4.y = sigmoidf_(ts * (sa1.y + sg1.y) + tbv);
  pb4.z = sigmoidf_(ts * (sa1.z + sg1.z) + tbv);
  pb4.w = sigmoidf_(ts * (sa1.w + sg1.w) + tbv);
  const float* f0 = featmap + (size_t)(b * 8 + 2 * p) * 262144 + (size_t)c * 128 + h4;
  const float* f1 = f0 + 262144;
  float4 v0 = *(const float4*)f0;
  float4 v1 = *(const float4*)f1;
  float4 o4;
  float r;
  r = fmaxf(ga * pa4.x * v0.x + gb * pb4.x * v1.x, 0.f); o4.x = r * r;
  r = fmaxf(ga * pa4.y * v0.y + gb * pb4.y * v1.y, 0.f); o4.y = r * r;
  r = fmaxf(ga * pa4.z * v0.z + gb * pb4.z * v1.z, 0.f); o4.z = r * r;
  r = fmaxf(ga * pa4.w * v0.w + gb * pb4.w * v1.w, 0.f); o4.w = r * r;
  *(float4*)(out + (size_t)fid * 4) = o4;
}

extern "C" void kernel_launch(void* const* d_in, const int* in_sizes, int n_in,
                              void* d_out, int out_size, void* d_ws, size_t ws_size,
                              hipStream_t stream) {
  (void)in_sizes; (void)n_in; (void)out_size; (void)ws_size;
  const float* featmap    = (const float*)d_in[0];
  const float* re_featmap = (const float*)d_in[1];
  const float* vect       = (const float*)d_in[2];
  const float* embed      = (const float*)d_in[3];
  const float* gamma_w    = (const float*)d_in[4];
  const float* gamma_s    = (const float*)d_in[5];
  const float* gamma_b    = (const float*)d_in[6];
  const float* beta_w     = (const float*)d_in[7];
  const float* beta_s     = (const float*)d_in[8];
  const float* beta_b     = (const float*)d_in[9];
  const float* gg_w       = (const float*)d_in[10];
  const float* gg_s       = (const float*)d_in[11];
  const float* gg_b       = (const float*)d_in[12];
  const float* tte_w      = (const float*)d_in[13];
  const float* tte_s      = (const float*)d_in[14];
  const float* tte_b      = (const float*)d_in[15];
  const float* te_w       = (const float*)d_in[16];
  const float* te_s       = (const float*)d_in[17];
  const float* te_b       = (const float*)d_in[18];
  const float* theta_w    = (const float*)d_in[19];
  const float* theta_b    = (const float*)d_in[20];
  const float* cp_w1      = (const float*)d_in[21];
  const float* cp_b1      = (const float*)d_in[22];
  const float* cp_w2      = (const float*)d_in[23];
  const float* cp_b2      = (const float*)d_in[24];
  float* out = (float*)d_out;

  char* w = (char*)d_ws;
  f16* Wf  = (f16*)w;   w += (size_t)512 * 2048 * 2;
  f16* gammaFh = (f16*)w; w += (size_t)128 * 256 * 128 * 2;
  f16* betaFh  = (f16*)w; w += (size_t)128 * 256 * 128 * 2;
  float* Gs0    = (float*)w; w += (size_t)64 * 128 * 128 * 4;
  float* Gs1    = (float*)w; w += (size_t)64 * 128 * 128 * 4;
  float* ggT    = (float*)w; w += (size_t)256 * 128 * 4;
  float* tteT   = (float*)w; w += (size_t)256 * 128 * 4;
  float* thwT   = (float*)w; w += (size_t)2048 * 256 * 4;
  float* w1T    = (float*)w; w += (size_t)512 * 256 * 4;
  float* w2T    = (float*)w; w += (size_t)256 * 2048 * 4;
  float* P      = (float*)w; w += (size_t)4 * 128 * 256 * 4;
  float* h1     = (float*)w; w += (size_t)64 * 2 * 256 * 4;
  float* Sta    = (float*)w; w += (size_t)2 * 64 * 128 * 4;
  float* Sgj    = (float*)w; w += (size_t)2 * 64 * 128 * 4;
  float* p00    = (float*)w; w += (size_t)64 * 2048 * 4;
  float* p01    = (float*)w; w += (size_t)64 * 2048 * 4;

  kPP<<<816, 256, 0, stream>>>(gamma_w, gamma_s, beta_w, beta_s, gg_w, gg_s, tte_w, tte_s,
                               theta_w, cp_w1, cp_w2, Wf, ggT, tteT, thwT, w1T, w2T);
  kGemm8<<<512, 512, 0, stream>>>(re_featmap, Wf, gamma_b, beta_b, gammaFh, betaFh);
  kTT<<<768, 256, 0, stream>>>(vect, thwT, P, embed, tteT, tte_b, te_w, Sta);
  kAG<<<512, 256, 0, stream>>>(P, theta_b, w1T, cp_b1, h1, gammaFh, betaFh, Gs0, Gs1);
  kBG<<<768, 256, 0, stream>>>(h1, w2T, cp_b2, p00, p01, Gs0, Gs1, ggT, gg_b, te_w, Sgj);
  kFinal<<<16384, 256, 0, stream>>>(featmap, p00, p01, Sta, Sgj, te_s, te_b, out);
}